// Round 1
// baseline (131.641 us; speedup 1.0000x reference)
//
#include <hip/hip_runtime.h>
#include <hip/hip_bf16.h>
#include <stdint.h>

// Problem shape (fixed by reference)
#define B_ 32
#define T_ 1024
#define J_ 256
#define D_ 512

typedef __attribute__((ext_vector_type(8))) short short8;   // 8 bf16 (4 VGPRs)
typedef __attribute__((ext_vector_type(4))) float floatx4;  // MFMA C/D frag

// ---------------------------------------------------------------------------
// Kernel 1: prep_u — B2[j,k] = bf16(u[j,k]*w_m[k] + w_h[k]),
//                    tu[j]   = sum_k u[j,k]*w_u[k]   (fp32)
// Identity: out[t,j] = sum_k h[t,k]*B2[j,k] + tu[j]
// ---------------------------------------------------------------------------
__global__ __launch_bounds__(256) void prep_u_kernel(
    const float* __restrict__ u, const float* __restrict__ w,
    __hip_bfloat16* __restrict__ B2, float* __restrict__ tu)
{
    int row  = blockIdx.x * 4 + (threadIdx.x >> 6);   // one wave per u-row
    int lane = threadIdx.x & 63;
    const float* src = u + (size_t)row * D_;
    int base = lane * 8;

    float4 v0  = *(const float4*)(src + base);
    float4 v1  = *(const float4*)(src + base + 4);
    float4 wh0 = *(const float4*)(w + base);            // w_h = w[0:512]
    float4 wh1 = *(const float4*)(w + base + 4);
    float4 wu0 = *(const float4*)(w + D_ + base);       // w_u = w[512:1024]
    float4 wu1 = *(const float4*)(w + D_ + base + 4);
    float4 wm0 = *(const float4*)(w + 2*D_ + base);     // w_m = w[1024:1536]
    float4 wm1 = *(const float4*)(w + 2*D_ + base + 4);

    float s = v0.x*wu0.x + v0.y*wu0.y + v0.z*wu0.z + v0.w*wu0.w
            + v1.x*wu1.x + v1.y*wu1.y + v1.z*wu1.z + v1.w*wu1.w;

    float vals[8] = {
        v0.x*wm0.x + wh0.x, v0.y*wm0.y + wh0.y,
        v0.z*wm0.z + wh0.z, v0.w*wm0.w + wh0.w,
        v1.x*wm1.x + wh1.x, v1.y*wm1.y + wh1.y,
        v1.z*wm1.z + wh1.z, v1.w*wm1.w + wh1.w };

    union { __hip_bfloat16 b[8]; uint4 q; } pk;
#pragma unroll
    for (int i = 0; i < 8; i++) pk.b[i] = __float2bfloat16(vals[i]);
    *(uint4*)(B2 + (size_t)row * D_ + base) = pk.q;     // 16B coalesced store

#pragma unroll
    for (int off = 32; off > 0; off >>= 1) s += __shfl_down(s, off, 64);
    if (lane == 0) tu[row] = s;
}

// ---------------------------------------------------------------------------
// Kernel 2: fused GEMM  out[b] = bf16(h[b]) @ B2[b]^T + tu
//
// Round-9 restructure (from R8's 128x256/1024thr/1-block-per-CU):
//  - 64x256 tile, 512 thr (8 waves, 4x2), BK=64, LDS 2x32KB = 64 KB
//    -> 2 blocks/CU: barrier-drain stalls of one block are covered by the
//       other block's compute/loads (R8 had zero TLP at every phase barrier).
//  - full-J tile kept: h still read EXACTLY once (no J-split => no h re-read).
//  - grid x = batch: linear id = b + 32*tM -> XCD b%8, B2[b] L2-resident (R8).
//  - counted-vmcnt barriers (T4): s_waitcnt vmcnt(4) + s_barrier. The 4
//    newest outstanding VMEM ops at every barrier are the A-prefetch loads;
//    vmcnt(4) drains the 4 global_load_lds DMAs but keeps A in flight across
//    the barrier (syncthreads' vmcnt(0) was force-draining ~900cy HBM loads).
//  - A-prefetch 2 k-steps deep via even(aA)/odd(aB) register banks, static
//    indexing, no register moves.
//  - sched_barrier(0) after each DMA-issue block pins VMEM issue order so the
//    vmcnt(4) count is exact (DMAs oldest, A-loads newest).
// ---------------------------------------------------------------------------
__device__ inline void gload_lds16(const void* g, void* l) {
    __builtin_amdgcn_global_load_lds(
        (__attribute__((address_space(1))) void*)(g),
        (__attribute__((address_space(3))) void*)(l),
        16, 0, 0);
}

__global__ __launch_bounds__(512, 4) void gemm_kernel(
    const float* __restrict__ h,            // [B, T, D] fp32
    const __hip_bfloat16* __restrict__ B2,  // [B, J, D] bf16 (= u*w_m + w_h)
    const float* __restrict__ tu,           // [B*J] fp32
    float* __restrict__ out)                // [B, T, J] fp32
{
    __shared__ __align__(16) __hip_bfloat16 sB[2][256 * 64];  // 2 x 32 KB

    const int b   = blockIdx.x;             // batch -> XCD b%8 (L2 locality)
    const int tM  = blockIdx.y;             // T/64 = 16 tiles
    const int tid = threadIdx.x;
    const int w = tid >> 6, lane = tid & 63;
    const int wr = w >> 1, wc = w & 1;      // 4x2 wave grid

    const int fr = lane & 15;               // row within 16-tile (m or n)
    const int kq = lane >> 4;               // k-quarter 0..3

    // this wave's 16 A-rows; lane reads row fr, k-slice kq*8
    const float* Aw = h + ((size_t)b * T_ + tM * 64 + wr * 16 + fr) * D_ + kq * 8;
    const __hip_bfloat16* Bb = B2 + (size_t)b * J_ * D_;

    floatx4 acc[8];
#pragma unroll
    for (int n = 0; n < 8; n++) acc[n] = (floatx4)0.0f;

    // ---- stage phase 0 into buffer 0 (2048 x 16B chunks, 4 per thread)
    // LDS chunk (j, c) <- source chunk c^(j&7) of row j (XOR swizzle so the
    // ds_read_b128 column reads spread across banks; 2-way max = free).
#pragma unroll
    for (int i = 0; i < 4; i++) {
        int q = i * 512 + tid;              // lane-linear LDS chunk
        int j = q >> 3;                     // j row 0..255
        int c = (q & 7) ^ (j & 7);          // source k-chunk (XOR swizzle)
        gload_lds16(Bb + (size_t)j * D_ + c * 8, &sB[0][q * 8]);
    }
    __builtin_amdgcn_sched_barrier(0);      // DMAs issue before A loads

    // ---- A pipeline: 2 k-steps deep, even/odd banks (ki=0 -> aA, ki=1 -> aB)
    float4 aA0 = *(const float4*)(Aw);
    float4 aA1 = *(const float4*)(Aw + 4);
    float4 aB0 = *(const float4*)(Aw + 32);
    float4 aB1 = *(const float4*)(Aw + 36);

    // drain the 4 DMAs (oldest), keep the 4 A-loads in flight
    asm volatile("s_waitcnt vmcnt(4) lgkmcnt(0)\n\ts_barrier" ::: "memory");

    for (int p = 0; p < 8; p++) {           // 8 phases of K=64
        // ---- async prefetch of phase p+1 into the other buffer
        if (p < 7) {
#pragma unroll
            for (int i = 0; i < 4; i++) {
                int q = i * 512 + tid;
                int j = q >> 3;
                int c = (q & 7) ^ (j & 7);
                gload_lds16(Bb + (size_t)j * D_ + (p + 1) * 64 + c * 8,
                            &sB[(p + 1) & 1][q * 8]);
            }
            __builtin_amdgcn_sched_barrier(0);  // keep DMAs oldest in vmcnt
        }
        const __hip_bfloat16* sBp = sB[p & 1];

        // ---- ks = 0 (ki = 2p, even bank aA)
        {
            union { __hip_bfloat16 e[8]; short8 v; } af;
            af.e[0]=__float2bfloat16(aA0.x); af.e[1]=__float2bfloat16(aA0.y);
            af.e[2]=__float2bfloat16(aA0.z); af.e[3]=__float2bfloat16(aA0.w);
            af.e[4]=__float2bfloat16(aA1.x); af.e[5]=__float2bfloat16(aA1.y);
            af.e[6]=__float2bfloat16(aA1.z); af.e[7]=__float2bfloat16(aA1.w);
            if (p < 7) {                    // refill aA for ki = 2p+2
                const float* ap = Aw + (2 * p + 2) * 32;
                aA0 = *(const float4*)(ap);
                aA1 = *(const float4*)(ap + 4);
            }
#pragma unroll
            for (int n = 0; n < 8; n++) {
                int j = wc * 128 + n * 16 + fr;
                int cc = kq;                // k-chunk 0..3 within phase
                short8 bf = *(const short8*)(sBp + (j * 8 + (cc ^ (j & 7))) * 8);
                acc[n] = __builtin_amdgcn_mfma_f32_16x16x32_bf16(
                    af.v, bf, acc[n], 0, 0, 0);
            }
        }
        // ---- ks = 1 (ki = 2p+1, odd bank aB)
        {
            union { __hip_bfloat16 e[8]; short8 v; } af;
            af.e[0]=__float2bfloat16(aB0.x); af.e[1]=__float2bfloat16(aB0.y);
            af.e[2]=__float2bfloat16(aB0.z); af.e[3]=__float2bfloat16(aB0.w);
            af.e[4]=__float2bfloat16(aB1.x); af.e[5]=__float2bfloat16(aB1.y);
            af.e[6]=__float2bfloat16(aB1.z); af.e[7]=__float2bfloat16(aB1.w);
            if (p < 7) {                    // refill aB for ki = 2p+3
                const float* ap = Aw + (2 * p + 3) * 32;
                aB0 = *(const float4*)(ap);
                aB1 = *(const float4*)(ap + 4);
            }
#pragma unroll
            for (int n = 0; n < 8; n++) {
                int j = wc * 128 + n * 16 + fr;
                int cc = 4 + kq;            // k-chunk 4..7 within phase
                short8 bf = *(const short8*)(sBp + (j * 8 + (cc ^ (j & 7))) * 8);
                acc[n] = __builtin_amdgcn_mfma_f32_16x16x32_bf16(
                    af.v, bf, acc[n], 0, 0, 0);
            }
        }
        // ---- phase handoff: drain this phase's 4 DMAs (oldest outstanding),
        // leave the 4 just-issued A-prefetch loads in flight across s_barrier
        if (p < 7)
            asm volatile("s_waitcnt vmcnt(4) lgkmcnt(0)\n\ts_barrier" ::: "memory");
    }

    // epilogue: C/D layout col = lane&15, row = (lane>>4)*4 + reg  [m89/m91]
    const size_t outB = (size_t)b * T_ * J_;
    const int r0 = tM * 64 + wr * 16 + kq * 4;
    const float* tub = tu + b * J_;
#pragma unroll
    for (int n = 0; n < 8; n++) {
        int col = wc * 128 + n * 16 + fr;
        float tuv = tub[col];
#pragma unroll
        for (int r = 0; r < 4; r++) {
            out[outB + (size_t)(r0 + r) * J_ + col] = acc[n][r] + tuv;
        }
    }
}

// ---------------------------------------------------------------------------
extern "C" void kernel_launch(void* const* d_in, const int* in_sizes, int n_in,
                              void* d_out, int out_size, void* d_ws, size_t ws_size,
                              hipStream_t stream)
{
    const float* h = (const float*)d_in[0];
    const float* u = (const float*)d_in[1];
    const float* w = (const float*)d_in[2];
    float* out = (float*)d_out;

    uint8_t* ws = (uint8_t*)d_ws;
    __hip_bfloat16* B2 = (__hip_bfloat16*)ws;                 // 8 MiB
    float* tu = (float*)(ws + (size_t)B_ * J_ * D_ * 2);      // 32 KiB

    // one wave per u-row; 4 rows per 256-thread block; 8192 rows total
    prep_u_kernel<<<dim3(B_ * J_ / 4), 256, 0, stream>>>(u, w, B2, tu);

    // 64x256 tiles (full J): x = batch (XCD locality), y = tM; 2 blocks/CU
    gemm_kernel<<<dim3(B_, T_ / 64), 512, 0, stream>>>(h, B2, tu, out);
}

// Round 6
// 127.844 us; speedup vs baseline: 1.0297x; 1.0297x over previous
//
#include <hip/hip_runtime.h>
#include <hip/hip_bf16.h>
#include <stdint.h>

// Problem shape (fixed by reference)
#define B_ 32
#define T_ 1024
#define J_ 256
#define D_ 512

typedef __attribute__((ext_vector_type(8))) short short8;   // 8 bf16 (4 VGPRs)
typedef __attribute__((ext_vector_type(4))) float floatx4;  // MFMA C/D frag

// ---------------------------------------------------------------------------
// Round-14 == Round-0 kernel restored VERBATIM (harness-verified: 127.7us,
// absmax 0.0625). Rationale: the fused single-kernel variants (R10/R12/R13)
// all fail absmax ~0.7-0.8 with a deterministic, tiny corruption in the
// computed B-staging path that survived three full audits (staging map
// proven element-identical to this kernel's DMA layout; no barrier-window
// race; tu exonerated by R13's hardened reduction). Three failed hardware
// rounds = stop-loss; bank the verified best.
// ---------------------------------------------------------------------------

// Kernel 1: prep_u — B2[j,k] = bf16(u[j,k]*w_m[k] + w_h[k]),
//                    tu[j]   = sum_k u[j,k]*w_u[k]   (fp32)
// Identity: out[t,j] = sum_k h[t,k]*B2[j,k] + tu[j]
__global__ __launch_bounds__(256) void prep_u_kernel(
    const float* __restrict__ u, const float* __restrict__ w,
    __hip_bfloat16* __restrict__ B2, float* __restrict__ tu)
{
    int row  = blockIdx.x * 4 + (threadIdx.x >> 6);   // one wave per u-row
    int lane = threadIdx.x & 63;
    const float* src = u + (size_t)row * D_;
    int base = lane * 8;

    float4 v0  = *(const float4*)(src + base);
    float4 v1  = *(const float4*)(src + base + 4);
    float4 wh0 = *(const float4*)(w + base);            // w_h = w[0:512]
    float4 wh1 = *(const float4*)(w + base + 4);
    float4 wu0 = *(const float4*)(w + D_ + base);       // w_u = w[512:1024]
    float4 wu1 = *(const float4*)(w + D_ + base + 4);
    float4 wm0 = *(const float4*)(w + 2*D_ + base);     // w_m = w[1024:1536]
    float4 wm1 = *(const float4*)(w + 2*D_ + base + 4);

    float s = v0.x*wu0.x + v0.y*wu0.y + v0.z*wu0.z + v0.w*wu0.w
            + v1.x*wu1.x + v1.y*wu1.y + v1.z*wu1.z + v1.w*wu1.w;

    float vals[8] = {
        v0.x*wm0.x + wh0.x, v0.y*wm0.y + wh0.y,
        v0.z*wm0.z + wh0.z, v0.w*wm0.w + wh0.w,
        v1.x*wm1.x + wh1.x, v1.y*wm1.y + wh1.y,
        v1.z*wm1.z + wh1.z, v1.w*wm1.w + wh1.w };

    union { __hip_bfloat16 b[8]; uint4 q; } pk;
#pragma unroll
    for (int i = 0; i < 8; i++) pk.b[i] = __float2bfloat16(vals[i]);
    *(uint4*)(B2 + (size_t)row * D_ + base) = pk.q;     // 16B coalesced store

#pragma unroll
    for (int off = 32; off > 0; off >>= 1) s += __shfl_down(s, off, 64);
    if (lane == 0) tu[row] = s;
}

// ---------------------------------------------------------------------------
// Kernel 2: fused GEMM  out[b] = bf16(h[b]) @ B2[b]^T + tu
//  - 128x256 tile, 1024 thr (16 waves, 8x2), 256 blocks = 1/CU.
//  - grid x = batch, y = tM: linear id = b + 32*tM -> all 8 tM-blocks of
//    batch b land on XCD b%8 -> B2[b] (512 KB) L2-resident.
//  - B2 staged async (global_load_lds), 4 phases of K=128, double-buffered.
//  - explicit 1-step A register prefetch across the WHOLE K-loop.
// ---------------------------------------------------------------------------
__device__ inline void gload_lds16(const void* g, void* l) {
    __builtin_amdgcn_global_load_lds(
        (__attribute__((address_space(1))) void*)(g),
        (__attribute__((address_space(3))) void*)(l),
        16, 0, 0);
}

__global__ __launch_bounds__(1024, 4) void gemm_kernel(
    const float* __restrict__ h,            // [B, T, D] fp32
    const __hip_bfloat16* __restrict__ B2,  // [B, J, D] bf16 (= u*w_m + w_h)
    const float* __restrict__ tu,           // [B*J] fp32
    float* __restrict__ out)                // [B, T, J] fp32
{
    __shared__ __align__(16) __hip_bfloat16 sB[2][256 * 128];  // 2 x 64 KB

    const int b   = blockIdx.x;             // batch -> XCD b%8 (locality)
    const int tM  = blockIdx.y;             // T/128 = 8 tiles
    const int tid = threadIdx.x;
    const int w = tid >> 6, lane = tid & 63;
    const int wr = w >> 1, wc = w & 1;      // 8x2 wave grid

    const int fr = lane & 15;               // row within 16-tile (m or n)
    const int kq = lane >> 4;               // k-quarter 0..3

    // this wave's 16 A-rows; lane reads row fr, k-slice kq*8
    const float* Aw = h + ((size_t)b * T_ + tM * 128 + wr * 16 + fr) * D_ + kq * 8;
    const __hip_bfloat16* Bb = B2 + (size_t)b * J_ * D_;

    floatx4 acc[8];
#pragma unroll
    for (int n = 0; n < 8; n++) acc[n] = (floatx4)0.0f;

    // ---- stage phase 0 into buffer 0 (4096 chunks, 4 per thread)
#pragma unroll
    for (int i = 0; i < 4; i++) {
        int q = i * 1024 + tid;             // lane-linear LDS chunk
        int j = q >> 4;
        int c = (q & 15) ^ (j & 15);        // source k-chunk (XOR swizzle)
        gload_lds16(Bb + (size_t)j * D_ + c * 8, &sB[0][q * 8]);
    }

    // ---- A prefetch pipeline: aC = k-step 0 (issued before the barrier,
    // overlaps the phase-0 DMA drain)
    float4 aC0 = *(const float4*)(Aw);
    float4 aC1 = *(const float4*)(Aw + 4);
    float4 aN0, aN1;
    __syncthreads();

    for (int p = 0; p < 4; p++) {
        // ---- async prefetch of phase p+1 into the other buffer
        if (p < 3) {
#pragma unroll
            for (int i = 0; i < 4; i++) {
                int q = i * 1024 + tid;
                int j = q >> 4;
                int c = (q & 15) ^ (j & 15);
                gload_lds16(Bb + (size_t)j * D_ + (p + 1) * 128 + c * 8,
                            &sB[(p + 1) & 1][q * 8]);
            }
        }
        const __hip_bfloat16* sBp = sB[p & 1];

        // ---- 4 k-steps; A loads run one step ahead (global, no barriers)
#pragma unroll
        for (int ks = 0; ks < 4; ks++) {
            int ki = p * 4 + ks;
            if (ki < 15) {                  // issue NEXT A load now
                const float* ap = Aw + (ki + 1) * 32;
                aN0 = *(const float4*)(ap);
                aN1 = *(const float4*)(ap + 4);
            }
            union { __hip_bfloat16 e[8]; short8 v; } af;
            af.e[0]=__float2bfloat16(aC0.x); af.e[1]=__float2bfloat16(aC0.y);
            af.e[2]=__float2bfloat16(aC0.z); af.e[3]=__float2bfloat16(aC0.w);
            af.e[4]=__float2bfloat16(aC1.x); af.e[5]=__float2bfloat16(aC1.y);
            af.e[6]=__float2bfloat16(aC1.z); af.e[7]=__float2bfloat16(aC1.w);
#pragma unroll
            for (int n = 0; n < 8; n++) {
                int j = wc * 128 + n * 16 + fr;
                int c = ks * 4 + kq;
                short8 bf = *(const short8*)(sBp + (j * 16 + (c ^ (j & 15))) * 8);
                acc[n] = __builtin_amdgcn_mfma_f32_16x16x32_bf16(
                    af.v, bf, acc[n], 0, 0, 0);
            }
            if (ki < 15) { aC0 = aN0; aC1 = aN1; }
        }
        __syncthreads();   // phase handoff (DMAs aged a full phase)
    }

    // epilogue: C/D layout col = lane&15, row = (lane>>4)*4 + reg  [m89/m91]
    const size_t outB = (size_t)b * T_ * J_;
    const int r0 = tM * 128 + wr * 16 + kq * 4;
    const float* tub = tu + b * J_;
#pragma unroll
    for (int n = 0; n < 8; n++) {
        int col = wc * 128 + n * 16 + fr;
        float tuv = tub[col];
#pragma unroll
        for (int r = 0; r < 4; r++) {
            out[outB + (size_t)(r0 + r) * J_ + col] = acc[n][r] + tuv;
        }
    }
}

// ---------------------------------------------------------------------------
extern "C" void kernel_launch(void* const* d_in, const int* in_sizes, int n_in,
                              void* d_out, int out_size, void* d_ws, size_t ws_size,
                              hipStream_t stream)
{
    const float* h = (const float*)d_in[0];
    const float* u = (const float*)d_in[1];
    const float* w = (const float*)d_in[2];
    float* out = (float*)d_out;

    uint8_t* ws = (uint8_t*)d_ws;
    __hip_bfloat16* B2 = (__hip_bfloat16*)ws;                 // 8 MiB
    float* tu = (float*)(ws + (size_t)B_ * J_ * D_ * 2);      // 32 KiB

    // one wave per u-row; 4 rows per 256-thread block; 8192 rows total
    prep_u_kernel<<<dim3(B_ * J_ / 4), 256, 0, stream>>>(u, w, B2, tu);

    // 128x256 tiles (full J): x = batch (XCD locality), y = tM
    gemm_kernel<<<dim3(B_, T_ / 128), 1024, 0, stream>>>(h, B2, tu, out);
}